// Round 6
// baseline (751.172 us; speedup 1.0000x reference)
//
#include <hip/hip_runtime.h>
#include <hip/hip_bf16.h>

// ---- problem constants ----
#define MOD   3
#define BATCH 65536
#define EDIM  512
#define ADIM  256
#define FEAT  1536   // MOD*EDIM

// ---- types ----
typedef __attribute__((ext_vector_type(8))) short   s16x8;
typedef __attribute__((ext_vector_type(8))) __bf16  bf16x8;
typedef __attribute__((ext_vector_type(4))) float   f32x4;
typedef __attribute__((ext_vector_type(4))) unsigned short u16x4;

__device__ __forceinline__ float b2f(unsigned short u) {
    union { unsigned int ui; float f; } c; c.ui = ((unsigned int)u) << 16; return c.f;
}
__device__ __forceinline__ unsigned short f2b(float f) {
    __hip_bfloat16 h = __float2bfloat16(f);
    return __builtin_bit_cast(unsigned short, h);
}

// async global->LDS, 16B per lane (wave-uniform LDS base; HW adds lane*16)
__device__ __forceinline__ void glds16(const unsigned short* g, unsigned short* l) {
    __builtin_amdgcn_global_load_lds(
        (const __attribute__((address_space(1))) void*)g,
        (__attribute__((address_space(3))) void*)l, 16, 0, 0);
}

#define WAITV(N) asm volatile("s_waitcnt vmcnt(%0)" :: "i"(N) : "memory")
#define SCHED0() __builtin_amdgcn_sched_barrier(0)
__device__ __forceinline__ void BAR() {
    asm volatile("" ::: "memory");
    __builtin_amdgcn_s_barrier();
    asm volatile("" ::: "memory");
}

// ============ kernel 0: x f32 -> bf16 bits ============
__global__ __launch_bounds__(256) void k_convert_x(const float* __restrict__ x,
                                                   unsigned short* __restrict__ xb, int n4) {
    int i = blockIdx.x * blockDim.x + threadIdx.x;
    int stride = gridDim.x * blockDim.x;
    for (; i < n4; i += stride) {
        f32x4 v = *((const f32x4*)x + i);
        u16x4 o;
        for (int j = 0; j < 4; ++j) o[j] = f2b(v[j]);
        *((u16x4*)xb + i) = o;
    }
}

// ============ kernel 1: weight prep ============
// wqk [m][n(512)][e]:  n<256 -> Wq[m][e][n] else Wk[m][e][n-256]
// wtt3[q][k'(2)][f(512)][e]: k'=0 -> k=(q+1)%3, k'=1 -> k=(q+2)%3; = Wt[q][k][e][f]
__global__ __launch_bounds__(256) void k_prep_w(const float* __restrict__ Wq,
                                                const float* __restrict__ Wk,
                                                const float* __restrict__ Wt,
                                                unsigned short* __restrict__ wqk,
                                                unsigned short* __restrict__ wtt3) {
    int i = blockIdx.x * blockDim.x + threadIdx.x;
    int stride = gridDim.x * blockDim.x;
    for (int idx = i; idx < MOD * EDIM * EDIM; idx += stride) {
        int m = idx / (EDIM * EDIM); int r = idx % (EDIM * EDIM);
        int n = r / EDIM; int e = r % EDIM;
        float f = (n < ADIM) ? Wq[(m * EDIM + e) * ADIM + n]
                             : Wk[(m * EDIM + e) * ADIM + (n - ADIM)];
        wqk[idx] = f2b(f);
    }
    for (int idx = i; idx < MOD * 1024 * EDIM; idx += stride) {
        int q = idx / (1024 * EDIM); int r = idx % (1024 * EDIM);
        int n = r / EDIM; int e = r % EDIM;
        int kp = n >> 9, f = n & 511;
        int k = (q + 1 + kp) % 3;
        wtt3[idx] = f2b(Wt[((size_t)(q * 3 + k) * EDIM + e) * EDIM + f]);
    }
}

// ================= 256x256-tile phase-split GEMM core (m201 ordering) =================
// 8 waves (wm=wid>>2, wn=wid&3), per-wave C = 128x64. K-tile = 64, 2 K-halves.
// Staging unit = (operand, K-half) = [256][32] bf16 = 16 KB; ring of 8 = 128 KB.
// Unit s = 4t + 2*ks + opB, panel = s>>5. Stage 6 units ahead, 1 unit per phase.
// Phase p: {pre: ds_read operands for MFMA(p) + stage(p+6) [+WAITV]} BAR
//          SCHED0 setprio 16xMFMA setprio SCHED0 BAR.
// ds_reads sit in the pre-barrier window so their latency drains under the
// previous phase's MFMA pipe backlog. Waits: WAITV(8) in pre(q1) guards tile's
// A1/B1 reads; WAITV(8) in pre(q3) guards next tile's A0/B0 (allow = 4 units
// x 2 glds/wave). Tails <8,4> then <0,0>. Slot-overwrite ledger: stage(s)
// overwrites unit s-8, whose last reader completed before the barrier that
// precedes the stage issue (verified per-phase).

struct GCtx {
    const unsigned short* pA[2];
    const unsigned short* pB[2];
    const unsigned short* lds;
    unsigned short* ldsW;
    int aoff, boff;
};

__device__ __forceinline__ void gctx_init(GCtx& c,
                                          const unsigned short* Ag0, const unsigned short* Ag1,
                                          const unsigned short* Bg0, const unsigned short* Bg1,
                                          unsigned short* lds) {
    const int tid = threadIdx.x, lane = tid & 63, wid = tid >> 6;
    const int wm = wid >> 2, wn = wid & 3;
    int stageRow = wid * 32 + (lane >> 2);
    int gsrc8 = ((lane & 3) ^ ((lane >> 3) & 3)) * 8;
    size_t so = (size_t)stageRow * 512 + gsrc8;
    c.pA[0] = Ag0 + so; c.pA[1] = Ag1 + so;
    c.pB[0] = Bg0 + so; c.pB[1] = Bg1 + so;
    c.lds = lds;
    c.ldsW = lds + wid * 1024;
    int swz8 = ((lane >> 4) ^ ((lane >> 1) & 3)) * 8;
    c.aoff = (wm * 128 + (lane & 15)) * 32 + swz8;
    c.boff = (wn * 64 + (lane & 15)) * 32 + swz8;
}

template<int NU>
__device__ __forceinline__ void stage_s(const GCtx& c, int s) {
    if (s >= NU) return;
    int p = s >> 5;
    int sp = s & 31;
    int colK = (sp >> 2) * 64 + (sp & 2) * 16;
    const unsigned short* src = ((sp & 1) ? c.pB[p] : c.pA[p]) + colK;
    unsigned short* dst = c.ldsW + (s & 7) * 8192;
    glds16(src, dst);
    glds16(src + 16 * 512, dst + 512);
}

// pre-section of phase Q of tile T: ds_read operands + stage one unit
template<int NU, int Q>
__device__ __forceinline__ void pre_phase(const GCtx& c, int T,
                                          s16x8 (&af)[4], s16x8 (&bfr)[4]) {
    constexpr int ks = Q >> 1, rh = Q & 1;
    const unsigned short* Asl = c.lds + ((T & 1) * 4 + 2 * ks) * 8192;
    const unsigned short* Bsl = Asl + 8192;
#pragma unroll
    for (int i = 0; i < 4; ++i) af[i] = *(const s16x8*)(Asl + c.aoff + (rh * 4 + i) * 512);
    if constexpr (rh == 0) {
#pragma unroll
        for (int j = 0; j < 4; ++j) bfr[j] = *(const s16x8*)(Bsl + c.boff + j * 512);
    }
    stage_s<NU>(c, 4 * T + 6 + Q);
}

template<int Q>
__device__ __forceinline__ void mfma_phase(s16x8 (&af)[4], s16x8 (&bfr)[4],
                                           f32x4 (&acc)[8][4]) {
    constexpr int rh = Q & 1;
    __builtin_amdgcn_s_setprio(1);
#pragma unroll
    for (int i = 0; i < 4; ++i)
#pragma unroll
        for (int j = 0; j < 4; ++j)
            acc[rh * 4 + i][j] = __builtin_amdgcn_mfma_f32_16x16x32_bf16(
                __builtin_bit_cast(bf16x8, af[i]), __builtin_bit_cast(bf16x8, bfr[j]),
                acc[rh * 4 + i][j], 0, 0, 0);
    __builtin_amdgcn_s_setprio(0);
}

template<int W1, int W3, int NU>
__device__ __forceinline__ void do_tile(int T, const GCtx& c,
                                        s16x8 (&af)[4], s16x8 (&bfr)[4],
                                        f32x4 (&acc)[8][4]) {
    pre_phase<NU, 0>(c, T, af, bfr);
    BAR(); SCHED0();
    mfma_phase<0>(af, bfr, acc);
    SCHED0(); BAR();

    pre_phase<NU, 1>(c, T, af, bfr);
    WAITV(W1);
    BAR(); SCHED0();
    mfma_phase<1>(af, bfr, acc);
    SCHED0(); BAR();

    pre_phase<NU, 2>(c, T, af, bfr);
    BAR(); SCHED0();
    mfma_phase<2>(af, bfr, acc);
    SCHED0(); BAR();

    pre_phase<NU, 3>(c, T, af, bfr);
    WAITV(W3);
    BAR(); SCHED0();
    mfma_phase<3>(af, bfr, acc);
    SCHED0(); BAR();
}

// ============ kernel 2: proj = X_m @ [Wq|Wk]_m + bias, bf16 out ============
__global__ __launch_bounds__(512, 2) void k_gemm_proj(const unsigned short* __restrict__ xb,
                                                      const unsigned short* __restrict__ wqk,
                                                      const float* __restrict__ bq,
                                                      const float* __restrict__ bk,
                                                      unsigned short* __restrict__ proj) {
    __shared__ __align__(16) unsigned short LDS[65536];
    int l = (blockIdx.x & 7) * 192 + (blockIdx.x >> 3);   // XCD-chunked, nwg=1536
    int ct = l & 1, rt = (l >> 1) & 255, m = l >> 9;
    int row0 = rt * 256, col0 = ct * 256;
    f32x4 acc[8][4];
#pragma unroll
    for (int i = 0; i < 8; ++i) for (int j = 0; j < 4; ++j) acc[i][j] = (f32x4)0.f;
    GCtx c;
    const unsigned short* Ag = xb + ((size_t)m * BATCH + row0) * EDIM;
    const unsigned short* Bg = wqk + ((size_t)m * EDIM + col0) * EDIM;
    gctx_init(c, Ag, Ag, Bg, Bg, LDS);
    s16x8 af[4], bfr[4];
#pragma unroll
    for (int s = 0; s < 6; ++s) stage_s<32>(c, s);
    WAITV(8);
    BAR();
#pragma unroll 1
    for (int t = 0; t < 6; ++t) do_tile<8, 8, 32>(t, c, af, bfr, acc);
    do_tile<8, 4, 32>(6, c, af, bfr, acc);
    do_tile<0, 0, 32>(7, c, af, bfr, acc);
    int lane = threadIdx.x & 63, wid = threadIdx.x >> 6;
    int wm = wid >> 2, wn = wid & 3;
#pragma unroll
    for (int j = 0; j < 4; ++j) {
        int col = col0 + wn * 64 + j * 16 + (lane & 15);
        float bias = (col < ADIM) ? bq[m * ADIM + col] : bk[m * ADIM + col - ADIM];
#pragma unroll
        for (int i8 = 0; i8 < 8; ++i8) {
            int rbase = row0 + wm * 128 + i8 * 16 + (lane >> 4) * 4;
#pragma unroll
            for (int r = 0; r < 4; ++r)
                proj[((size_t)m * BATCH + rbase + r) * EDIM + col] = f2b(acc[i8][j][r] + bias);
        }
    }
}

// ============ kernel 3: scores + softmax -> alpha[q*2+ki][b], k=(q+1+ki)%3 ============
__global__ __launch_bounds__(256) void k_scores(const unsigned short* __restrict__ proj,
                                                const float* __restrict__ v,
                                                float* __restrict__ alpha) {
    int wid = threadIdx.x >> 6, lane = threadIdx.x & 63;
    size_t b = (size_t)blockIdx.x * 4 + wid;
    float qp[3][4], kp[3][4], vq[3][4];
    for (int m = 0; m < 3; ++m) {
        const unsigned short* p = proj + ((size_t)m * BATCH + b) * EDIM;
        u16x4 uq = *(const u16x4*)(p + lane * 4);
        u16x4 uk = *(const u16x4*)(p + ADIM + lane * 4);
        f32x4 vv = *((const f32x4*)(v + m * ADIM) + lane);
        for (int j = 0; j < 4; ++j) { qp[m][j] = b2f(uq[j]); kp[m][j] = b2f(uk[j]); vq[m][j] = vv[j]; }
    }
    for (int q = 0; q < 3; ++q) {
        float s[2];
        for (int ki = 0; ki < 2; ++ki) {
            int k = (q + 1 + ki) % 3;
            float a = 0.f;
            for (int j = 0; j < 4; ++j) a += vq[q][j] * tanhf(qp[q][j] + kp[k][j]);
            for (int off = 32; off; off >>= 1) a += __shfl_xor(a, off, 64);
            s[ki] = a;
        }
        if (lane == 0) {
            float mx = fmaxf(s[0], s[1]);
            float e0 = expf(s[0] - mx), e1 = expf(s[1] - mx);
            float inv = 1.f / (e0 + e1);
            alpha[(size_t)(q * 2 + 0) * BATCH + b] = e0 * inv;
            alpha[(size_t)(q * 2 + 1) * BATCH + b] = e1 * inv;
        }
    }
}

// ============ kernel 4: att[q] = a0*(X_kA@WtA + btA) + a1*(X_kB@WtB + btB) ============
// Dual-panel K=1024, single acc via ratio trick (acc*=a0/a1 at panel boundary).
__global__ __launch_bounds__(512, 2) void k_gemm_att(const unsigned short* __restrict__ xb,
                                                     const unsigned short* __restrict__ wtt3,
                                                     const float* __restrict__ alpha,
                                                     const float* __restrict__ bt,
                                                     unsigned short* __restrict__ att) {
    __shared__ __align__(16) unsigned short LDS[65536];
    __shared__ float auxA0[256], auxA1[256], auxR[256];
    int l = (blockIdx.x & 7) * 192 + (blockIdx.x >> 3);   // XCD-chunked, nwg=1536
    int ct = l & 1, rt = (l >> 1) & 255, q = l >> 9;
    int row0 = rt * 256, col0 = ct * 256;
    int kA = (q + 1) % 3, kB = (q + 2) % 3;
    int tid = threadIdx.x, lane = tid & 63, wid = tid >> 6;
    int wm = wid >> 2, wn = wid & 3;

    if (tid < 256) {
        float a0 = alpha[(size_t)(q * 2 + 0) * BATCH + row0 + tid];
        float a1 = alpha[(size_t)(q * 2 + 1) * BATCH + row0 + tid];
        auxA0[tid] = a0; auxA1[tid] = a1;
        auxR[tid] = a0 / fmaxf(a1, 1e-30f);
    }
    __syncthreads();   // drains vmcnt(0): stage ledger starts clean

    f32x4 acc[8][4];
#pragma unroll
    for (int i = 0; i < 8; ++i) for (int j = 0; j < 4; ++j) acc[i][j] = (f32x4)0.f;
    GCtx c;
    gctx_init(c,
              xb + ((size_t)kA * BATCH + row0) * EDIM,
              xb + ((size_t)kB * BATCH + row0) * EDIM,
              wtt3 + ((size_t)(q * 2 + 0) * EDIM + col0) * EDIM,
              wtt3 + ((size_t)(q * 2 + 1) * EDIM + col0) * EDIM,
              LDS);
    s16x8 af[4], bfr[4];
#pragma unroll
    for (int s = 0; s < 6; ++s) stage_s<64>(c, s);
    WAITV(8);
    BAR();
#pragma unroll 1
    for (int t = 0; t < 8; ++t) do_tile<8, 8, 64>(t, c, af, bfr, acc);
    // ---- mid-scale: acc *= a0/a1 per row (panel boundary; registers only) ----
#pragma unroll
    for (int i8 = 0; i8 < 8; ++i8) {
        int rl = wm * 128 + i8 * 16 + (lane >> 4) * 4;
        f32x4 rv = *(const f32x4*)&auxR[rl];
#pragma unroll
        for (int j = 0; j < 4; ++j)
#pragma unroll
            for (int r = 0; r < 4; ++r) acc[i8][j][r] *= rv[r];
    }
#pragma unroll 1
    for (int t = 8; t < 14; ++t) do_tile<8, 8, 64>(t, c, af, bfr, acc);
    do_tile<8, 4, 64>(14, c, af, bfr, acc);
    do_tile<0, 0, 64>(15, c, af, bfr, acc);

    // ---- epilogue: att = a1*acc + a0*btA[col] + a1*btB[col] ----
    float btAv[4], btBv[4];
#pragma unroll
    for (int j = 0; j < 4; ++j) {
        int col = col0 + wn * 64 + j * 16 + (lane & 15);
        btAv[j] = bt[(size_t)(q * 3 + kA) * EDIM + col];
        btBv[j] = bt[(size_t)(q * 3 + kB) * EDIM + col];
    }
#pragma unroll
    for (int i8 = 0; i8 < 8; ++i8) {
        int rl = wm * 128 + i8 * 16 + (lane >> 4) * 4;
        f32x4 a0v = *(const f32x4*)&auxA0[rl];
        f32x4 a1v = *(const f32x4*)&auxA1[rl];
        int rbase = row0 + rl;
#pragma unroll
        for (int j = 0; j < 4; ++j) {
            int col = col0 + wn * 64 + j * 16 + (lane & 15);
#pragma unroll
            for (int r = 0; r < 4; ++r)
                att[((size_t)q * BATCH + rbase + r) * EDIM + col] =
                    f2b(a1v[r] * acc[i8][j][r] + a0v[r] * btAv[j] + a1v[r] * btBv[j]);
        }
    }
}

// ============ kernel 5: out = LN(xb + att) ============
__global__ __launch_bounds__(192) void k_fuse_ln(const unsigned short* __restrict__ xb,
                                                 const unsigned short* __restrict__ att,
                                                 const float* __restrict__ gamma,
                                                 const float* __restrict__ beta,
                                                 float* __restrict__ out) {
    __shared__ float red[2][3];
    int b = blockIdx.x, t = threadIdx.x, m = t >> 6, lane = t & 63;
    int e0 = lane * 8;
    s16x8 xv = *(const s16x8*)(xb + ((size_t)m * BATCH + b) * EDIM + e0);
    s16x8 av = *(const s16x8*)(att + ((size_t)m * BATCH + b) * EDIM + e0);
    float v[8]; float s = 0.f, s2 = 0.f;
#pragma unroll
    for (int j = 0; j < 8; ++j) {
        float vv = b2f((unsigned short)xv[j]) + b2f((unsigned short)av[j]);
        v[j] = vv; s += vv; s2 += vv * vv;
    }
    for (int off = 32; off; off >>= 1) { s += __shfl_xor(s, off, 64); s2 += __shfl_xor(s2, off, 64); }
    if (lane == 0) { red[0][m] = s; red[1][m] = s2; }
    __syncthreads();
    float S = red[0][0] + red[0][1] + red[0][2];
    float S2 = red[1][0] + red[1][1] + red[1][2];
    float mu  = S * (1.f / 1536.f);
    float var = S2 * (1.f / 1536.f) - mu * mu;
    float rs  = rsqrtf(var + 1e-5f);
    int f0 = m * EDIM + e0;
    f32x4 g0 = *(const f32x4*)(gamma + f0), g1 = *(const f32x4*)(gamma + f0 + 4);
    f32x4 be0 = *(const f32x4*)(beta + f0), be1 = *(const f32x4*)(beta + f0 + 4);
    f32x4 o0, o1;
#pragma unroll
    for (int j = 0; j < 4; ++j) {
        o0[j] = (v[j]     - mu) * rs * g0[j] + be0[j];
        o1[j] = (v[j + 4] - mu) * rs * g1[j] + be1[j];
    }
    float* op = out + (size_t)b * FEAT + f0;
    *(f32x4*)op = o0; *(f32x4*)(op + 4) = o1;
}

// ============ launcher ============
extern "C" void kernel_launch(void* const* d_in, const int* in_sizes, int n_in,
                              void* d_out, int out_size, void* d_ws, size_t ws_size,
                              hipStream_t stream) {
    const float* x     = (const float*)d_in[0];
    const float* Wq    = (const float*)d_in[1];
    const float* bq    = (const float*)d_in[2];
    const float* Wk    = (const float*)d_in[3];
    const float* bk    = (const float*)d_in[4];
    const float* v     = (const float*)d_in[5];
    const float* Wt    = (const float*)d_in[6];
    const float* bt    = (const float*)d_in[7];
    const float* gamma = (const float*)d_in[8];
    const float* beta  = (const float*)d_in[9];
    float* out = (float*)d_out;

    char* ws = (char*)d_ws;
    // layout (bytes):
    //   [0,         1572864)  wqk   bf16 3*512*512
    //   [1572864,   4718592)  wtt3  bf16 3*1024*512
    //   [4718592,   6291456)  alpha f32  6*65536
    //   [6291456, 207618048)  xb    bf16 3*65536*512
    //   [207618048,408944640) att   bf16 3*65536*512  (proj aliases; consumed first)
    unsigned short* wqk   = (unsigned short*)(ws);
    unsigned short* wtt3  = (unsigned short*)(ws + 1572864);
    float*          alpha = (float*)        (ws + 4718592);
    unsigned short* xb    = (unsigned short*)(ws + 6291456);
    unsigned short* att   = (unsigned short*)(ws + 207618048);
    unsigned short* proj  = att;  // proj fully consumed by k_scores before k_gemm_att writes att

    k_convert_x<<<4096, 256, 0, stream>>>(x, xb, (MOD * BATCH * EDIM) / 4);
    k_prep_w   <<<2048, 256, 0, stream>>>(Wq, Wk, Wt, wqk, wtt3);
    k_gemm_proj<<<1536, 512, 0, stream>>>(xb, wqk, bq, bk, proj);
    k_scores   <<<16384, 256, 0, stream>>>(proj, v, alpha);
    k_gemm_att <<<1536, 512, 0, stream>>>(xb, wtt3, alpha, bt, att);
    k_fuse_ln  <<<65536, 192, 0, stream>>>(xb, att, gamma, beta, out);
}

// Round 7
// 744.563 us; speedup vs baseline: 1.0089x; 1.0089x over previous
//
#include <hip/hip_runtime.h>
#include <hip/hip_bf16.h>

// ---- problem constants ----
#define MOD   3
#define BATCH 65536
#define EDIM  512
#define ADIM  256
#define FEAT  1536   // MOD*EDIM

// ---- types ----
typedef __attribute__((ext_vector_type(8))) short   s16x8;
typedef __attribute__((ext_vector_type(8))) __bf16  bf16x8;
typedef __attribute__((ext_vector_type(4))) float   f32x4;
typedef __attribute__((ext_vector_type(4))) unsigned short u16x4;

__device__ __forceinline__ float b2f(unsigned short u) {
    union { unsigned int ui; float f; } c; c.ui = ((unsigned int)u) << 16; return c.f;
}
__device__ __forceinline__ unsigned short f2b(float f) {
    __hip_bfloat16 h = __float2bfloat16(f);
    return __builtin_bit_cast(unsigned short, h);
}

// async global->LDS, 16B per lane (wave-uniform LDS base; HW adds lane*16)
__device__ __forceinline__ void glds16(const unsigned short* g, unsigned short* l) {
    __builtin_amdgcn_global_load_lds(
        (const __attribute__((address_space(1))) void*)g,
        (__attribute__((address_space(3))) void*)l, 16, 0, 0);
}

#define WAITV(N) asm volatile("s_waitcnt vmcnt(%0)" :: "i"(N) : "memory")
__device__ __forceinline__ void BAR() {
    asm volatile("" ::: "memory");
    __builtin_amdgcn_s_barrier();
    asm volatile("" ::: "memory");
}

// ============ kernel 0: x f32 -> bf16 bits ============
__global__ __launch_bounds__(256) void k_convert_x(const float* __restrict__ x,
                                                   unsigned short* __restrict__ xb, int n4) {
    int i = blockIdx.x * blockDim.x + threadIdx.x;
    int stride = gridDim.x * blockDim.x;
    for (; i < n4; i += stride) {
        f32x4 v = *((const f32x4*)x + i);
        u16x4 o;
        for (int j = 0; j < 4; ++j) o[j] = f2b(v[j]);
        *((u16x4*)xb + i) = o;
    }
}

// ============ kernel 1: weight prep ============
// wqk [m][n(512)][e]:  n<256 -> Wq[m][e][n] else Wk[m][e][n-256]
// wtt3[q][k'(2)][f(512)][e]: k'=0 -> k=(q+1)%3, k'=1 -> k=(q+2)%3; = Wt[q][k][e][f]
__global__ __launch_bounds__(256) void k_prep_w(const float* __restrict__ Wq,
                                                const float* __restrict__ Wk,
                                                const float* __restrict__ Wt,
                                                unsigned short* __restrict__ wqk,
                                                unsigned short* __restrict__ wtt3) {
    int i = blockIdx.x * blockDim.x + threadIdx.x;
    int stride = gridDim.x * blockDim.x;
    for (int idx = i; idx < MOD * EDIM * EDIM; idx += stride) {
        int m = idx / (EDIM * EDIM); int r = idx % (EDIM * EDIM);
        int n = r / EDIM; int e = r % EDIM;
        float f = (n < ADIM) ? Wq[(m * EDIM + e) * ADIM + n]
                             : Wk[(m * EDIM + e) * ADIM + (n - ADIM)];
        wqk[idx] = f2b(f);
    }
    for (int idx = i; idx < MOD * 1024 * EDIM; idx += stride) {
        int q = idx / (1024 * EDIM); int r = idx % (1024 * EDIM);
        int n = r / EDIM; int e = r % EDIM;
        int kp = n >> 9, f = n & 511;
        int k = (q + 1 + kp) % 3;
        wtt3[idx] = f2b(Wt[((size_t)(q * 3 + k) * EDIM + e) * EDIM + f]);
    }
}

// ================= 256x256-tile pipelined GEMM core =================
// 8 waves (wm=wid>>2, wn=wid&3), per-wave C = 128x64. K-tile = 64, 2 K-halves.
// Staging unit = (operand, K-half) = [256][32] bf16 = 16 KB; ring of 8 = 128 KB.
// Units: tile T -> A0=4T, B0=4T+1, A1=4T+2, B1=4T+3; phase p=4T+Q.
// Window w (one barrier each): BAR; ds_read operands of phase w+1 into the
// ALTERNATE register set (ping-pong: af[(Q+1)&1], bfr loaded on even target
// phases into bf[(Q+1)>>1... folds to bf1 at Q=1, bf0 at Q=3]); stage unit
// w+6; WAITV(6); setprio 16xMFMA(phase w, af[Q&1], bf[Q>>1]) setprio.
// Reads of w+1 fly concurrently with MFMA(w) pipe drain (no WAR: disjoint
// register sets). Compiler emits counted lgkm waits for the MFMA operands
// (they were read last window; the newer reads stay outstanding).
// vmcnt ledger: WAITV(6) at window v leaves units v+4..v+6 in flight =>
// units <= v+3 landed => window v+1's reads (phase v+2 needs units <= v+3) OK.
// Slot overwrite (unit u over u-8): last read of u-8 issued window <= u-8,
// forced complete by lgkm in window u-7; glds(u) issues after BAR(u-6). Safe.
// Tails: <6,6,4,2> then <0,0,0,0>; prologue stages units 0..5 + WAITV(8).

struct GCtx {
    const unsigned short* pA[2];
    const unsigned short* pB[2];
    const unsigned short* lds;
    unsigned short* ldsW;
    int aoff, boff;
};

__device__ __forceinline__ void gctx_init(GCtx& c,
                                          const unsigned short* Ag0, const unsigned short* Ag1,
                                          const unsigned short* Bg0, const unsigned short* Bg1,
                                          unsigned short* lds) {
    const int tid = threadIdx.x, lane = tid & 63, wid = tid >> 6;
    const int wm = wid >> 2, wn = wid & 3;
    int stageRow = wid * 32 + (lane >> 2);
    int gsrc8 = ((lane & 3) ^ ((lane >> 3) & 3)) * 8;
    size_t so = (size_t)stageRow * 512 + gsrc8;
    c.pA[0] = Ag0 + so; c.pA[1] = Ag1 + so;
    c.pB[0] = Bg0 + so; c.pB[1] = Bg1 + so;
    c.lds = lds;
    c.ldsW = lds + wid * 1024;
    int swz8 = ((lane >> 4) ^ ((lane >> 1) & 3)) * 8;
    c.aoff = (wm * 128 + (lane & 15)) * 32 + swz8;
    c.boff = (wn * 64 + (lane & 15)) * 32 + swz8;
}

template<int NU>
__device__ __forceinline__ void stage_s(const GCtx& c, int s) {
    if (s >= NU) return;
    int p = s >> 5;
    int sp = s & 31;
    int colK = (sp >> 2) * 64 + (sp & 2) * 16;
    const unsigned short* src = ((sp & 1) ? c.pB[p] : c.pA[p]) + colK;
    unsigned short* dst = c.ldsW + (s & 7) * 8192;
    glds16(src, dst);
    glds16(src + 16 * 512, dst + 512);
}

template<int Q, int W, int NU, bool DOREAD>
__device__ __forceinline__ void window_f(int T, const GCtx& c,
                                         s16x8 (&af0)[4], s16x8 (&af1)[4],
                                         s16x8 (&bf0)[4], s16x8 (&bf1)[4],
                                         f32x4 (&acc)[8][4]) {
    BAR();
    if constexpr (DOREAD) {
        constexpr int Qn = (Q + 1) & 3;          // quadrant of served phase (w+1)
        constexpr int ksn = Qn >> 1, rhn = Qn & 1;
        int Tn = (Q == 3) ? (T + 1) : T;
        const unsigned short* Asl = c.lds + ((Tn & 1) * 4 + 2 * ksn) * 8192;
        const unsigned short* Bsl = Asl + 8192;
#pragma unroll
        for (int i = 0; i < 4; ++i) {
            s16x8 v = *(const s16x8*)(Asl + c.aoff + (rhn * 4 + i) * 512);
            if constexpr ((Qn & 1) == 0) af0[i] = v; else af1[i] = v;
        }
        if constexpr (Qn == 0) {
#pragma unroll
            for (int j = 0; j < 4; ++j) bf0[j] = *(const s16x8*)(Bsl + c.boff + j * 512);
        }
        if constexpr (Qn == 2) {
#pragma unroll
            for (int j = 0; j < 4; ++j) bf1[j] = *(const s16x8*)(Bsl + c.boff + j * 512);
        }
    }
    stage_s<NU>(c, 4 * T + Q + 6);
    WAITV(W);
    __builtin_amdgcn_s_setprio(1);
    constexpr int RH = Q & 1;
#pragma unroll
    for (int i = 0; i < 4; ++i)
#pragma unroll
        for (int j = 0; j < 4; ++j) {
            const s16x8& a = (Q & 1) ? af1[i] : af0[i];   // constexpr condition: folds
            const s16x8& b = (Q >> 1) ? bf1[j] : bf0[j];
            acc[RH * 4 + i][j] = __builtin_amdgcn_mfma_f32_16x16x32_bf16(
                __builtin_bit_cast(bf16x8, a), __builtin_bit_cast(bf16x8, b),
                acc[RH * 4 + i][j], 0, 0, 0);
        }
    __builtin_amdgcn_s_setprio(0);
}

template<int W0, int W1, int W2, int W3, int NU, bool LASTT>
__device__ __forceinline__ void do_tile2(int T, const GCtx& c,
                                         s16x8 (&af0)[4], s16x8 (&af1)[4],
                                         s16x8 (&bf0)[4], s16x8 (&bf1)[4],
                                         f32x4 (&acc)[8][4]) {
    window_f<0, W0, NU, true  >(T, c, af0, af1, bf0, bf1, acc);
    window_f<1, W1, NU, true  >(T, c, af0, af1, bf0, bf1, acc);
    window_f<2, W2, NU, true  >(T, c, af0, af1, bf0, bf1, acc);
    window_f<3, W3, NU, !LASTT>(T, c, af0, af1, bf0, bf1, acc);
}

// prologue: stage units 0..5, publish 0,1, read phase 0 into set 0
template<int NU>
__device__ __forceinline__ void pipe_prologue(const GCtx& c,
                                              s16x8 (&af0)[4], s16x8 (&bf0)[4]) {
#pragma unroll
    for (int s = 0; s < 6; ++s) stage_s<NU>(c, s);
    WAITV(8);
    BAR();
    const unsigned short* Asl = c.lds;            // slot 0 = unit 0 (A0, tile 0)
    const unsigned short* Bsl = c.lds + 8192;     // slot 1 = unit 1 (B0, tile 0)
#pragma unroll
    for (int i = 0; i < 4; ++i) af0[i] = *(const s16x8*)(Asl + c.aoff + i * 512);
#pragma unroll
    for (int j = 0; j < 4; ++j) bf0[j] = *(const s16x8*)(Bsl + c.boff + j * 512);
}

// ============ kernel 2: proj = X_m @ [Wq|Wk]_m + bias, bf16 out ============
__global__ __launch_bounds__(512, 2) void k_gemm_proj(const unsigned short* __restrict__ xb,
                                                      const unsigned short* __restrict__ wqk,
                                                      const float* __restrict__ bq,
                                                      const float* __restrict__ bk,
                                                      unsigned short* __restrict__ proj) {
    __shared__ __align__(16) unsigned short LDS[65536];
    int l = (blockIdx.x & 7) * 192 + (blockIdx.x >> 3);   // XCD-chunked, nwg=1536
    int ct = l & 1, rt = (l >> 1) & 255, m = l >> 9;
    int row0 = rt * 256, col0 = ct * 256;
    f32x4 acc[8][4];
#pragma unroll
    for (int i = 0; i < 8; ++i) for (int j = 0; j < 4; ++j) acc[i][j] = (f32x4)0.f;
    GCtx c;
    const unsigned short* Ag = xb + ((size_t)m * BATCH + row0) * EDIM;
    const unsigned short* Bg = wqk + ((size_t)m * EDIM + col0) * EDIM;
    gctx_init(c, Ag, Ag, Bg, Bg, LDS);
    s16x8 af0[4], af1[4], bf0[4], bf1[4];
    pipe_prologue<32>(c, af0, bf0);
#pragma unroll 1
    for (int t = 0; t < 6; ++t) do_tile2<6, 6, 6, 6, 32, false>(t, c, af0, af1, bf0, bf1, acc);
    do_tile2<6, 6, 4, 2, 32, false>(6, c, af0, af1, bf0, bf1, acc);
    do_tile2<0, 0, 0, 0, 32, true >(7, c, af0, af1, bf0, bf1, acc);
    int lane = threadIdx.x & 63, wid = threadIdx.x >> 6;
    int wm = wid >> 2, wn = wid & 3;
#pragma unroll
    for (int j = 0; j < 4; ++j) {
        int col = col0 + wn * 64 + j * 16 + (lane & 15);
        float bias = (col < ADIM) ? bq[m * ADIM + col] : bk[m * ADIM + col - ADIM];
#pragma unroll
        for (int i8 = 0; i8 < 8; ++i8) {
            int rbase = row0 + wm * 128 + i8 * 16 + (lane >> 4) * 4;
#pragma unroll
            for (int r = 0; r < 4; ++r)
                proj[((size_t)m * BATCH + rbase + r) * EDIM + col] = f2b(acc[i8][j][r] + bias);
        }
    }
}

// ============ kernel 3: scores + softmax -> alpha[q*2+ki][b], k=(q+1+ki)%3 ============
__global__ __launch_bounds__(256) void k_scores(const unsigned short* __restrict__ proj,
                                                const float* __restrict__ v,
                                                float* __restrict__ alpha) {
    int wid = threadIdx.x >> 6, lane = threadIdx.x & 63;
    size_t b = (size_t)blockIdx.x * 4 + wid;
    float qp[3][4], kp[3][4], vq[3][4];
    for (int m = 0; m < 3; ++m) {
        const unsigned short* p = proj + ((size_t)m * BATCH + b) * EDIM;
        u16x4 uq = *(const u16x4*)(p + lane * 4);
        u16x4 uk = *(const u16x4*)(p + ADIM + lane * 4);
        f32x4 vv = *((const f32x4*)(v + m * ADIM) + lane);
        for (int j = 0; j < 4; ++j) { qp[m][j] = b2f(uq[j]); kp[m][j] = b2f(uk[j]); vq[m][j] = vv[j]; }
    }
    for (int q = 0; q < 3; ++q) {
        float s[2];
        for (int ki = 0; ki < 2; ++ki) {
            int k = (q + 1 + ki) % 3;
            float a = 0.f;
            for (int j = 0; j < 4; ++j) a += vq[q][j] * tanhf(qp[q][j] + kp[k][j]);
            for (int off = 32; off; off >>= 1) a += __shfl_xor(a, off, 64);
            s[ki] = a;
        }
        if (lane == 0) {
            float mx = fmaxf(s[0], s[1]);
            float e0 = expf(s[0] - mx), e1 = expf(s[1] - mx);
            float inv = 1.f / (e0 + e1);
            alpha[(size_t)(q * 2 + 0) * BATCH + b] = e0 * inv;
            alpha[(size_t)(q * 2 + 1) * BATCH + b] = e1 * inv;
        }
    }
}

// ============ kernel 4: att[q] = a0*(X_kA@WtA + btA) + a1*(X_kB@WtB + btB) ============
// Dual-panel K=1024, single acc via ratio trick (acc*=a0/a1 at panel boundary).
__global__ __launch_bounds__(512, 2) void k_gemm_att(const unsigned short* __restrict__ xb,
                                                     const unsigned short* __restrict__ wtt3,
                                                     const float* __restrict__ alpha,
                                                     const float* __restrict__ bt,
                                                     unsigned short* __restrict__ att) {
    __shared__ __align__(16) unsigned short LDS[65536];
    __shared__ float auxA0[256], auxA1[256], auxR[256];
    int l = (blockIdx.x & 7) * 192 + (blockIdx.x >> 3);   // XCD-chunked, nwg=1536
    int ct = l & 1, rt = (l >> 1) & 255, q = l >> 9;
    int row0 = rt * 256, col0 = ct * 256;
    int kA = (q + 1) % 3, kB = (q + 2) % 3;
    int tid = threadIdx.x, lane = tid & 63, wid = tid >> 6;
    int wm = wid >> 2, wn = wid & 3;

    if (tid < 256) {
        float a0 = alpha[(size_t)(q * 2 + 0) * BATCH + row0 + tid];
        float a1 = alpha[(size_t)(q * 2 + 1) * BATCH + row0 + tid];
        auxA0[tid] = a0; auxA1[tid] = a1;
        auxR[tid] = a0 / fmaxf(a1, 1e-30f);
    }
    __syncthreads();   // drains vmcnt(0): stage ledger starts clean

    f32x4 acc[8][4];
#pragma unroll
    for (int i = 0; i < 8; ++i) for (int j = 0; j < 4; ++j) acc[i][j] = (f32x4)0.f;
    GCtx c;
    gctx_init(c,
              xb + ((size_t)kA * BATCH + row0) * EDIM,
              xb + ((size_t)kB * BATCH + row0) * EDIM,
              wtt3 + ((size_t)(q * 2 + 0) * EDIM + col0) * EDIM,
              wtt3 + ((size_t)(q * 2 + 1) * EDIM + col0) * EDIM,
              LDS);
    s16x8 af0[4], af1[4], bf0[4], bf1[4];
    pipe_prologue<64>(c, af0, bf0);
#pragma unroll 1
    for (int t = 0; t < 8; ++t) do_tile2<6, 6, 6, 6, 64, false>(t, c, af0, af1, bf0, bf1, acc);
    // ---- mid-scale: acc *= a0/a1 per row (panel boundary; registers only) ----
#pragma unroll
    for (int i8 = 0; i8 < 8; ++i8) {
        int rl = wm * 128 + i8 * 16 + (lane >> 4) * 4;
        f32x4 rv = *(const f32x4*)&auxR[rl];
#pragma unroll
        for (int j = 0; j < 4; ++j)
#pragma unroll
            for (int r = 0; r < 4; ++r) acc[i8][j][r] *= rv[r];
    }
#pragma unroll 1
    for (int t = 8; t < 14; ++t) do_tile2<6, 6, 6, 6, 64, false>(t, c, af0, af1, bf0, bf1, acc);
    do_tile2<6, 6, 4, 2, 64, false>(14, c, af0, af1, bf0, bf1, acc);
    do_tile2<0, 0, 0, 0, 64, true >(15, c, af0, af1, bf0, bf1, acc);

    // ---- epilogue: att = a1*acc + a0*btA[col] + a1*btB[col] ----
    float btAv[4], btBv[4];
#pragma unroll
    for (int j = 0; j < 4; ++j) {
        int col = col0 + wn * 64 + j * 16 + (lane & 15);
        btAv[j] = bt[(size_t)(q * 3 + kA) * EDIM + col];
        btBv[j] = bt[(size_t)(q * 3 + kB) * EDIM + col];
    }
#pragma unroll
    for (int i8 = 0; i8 < 8; ++i8) {
        int rl = wm * 128 + i8 * 16 + (lane >> 4) * 4;
        f32x4 a0v = *(const f32x4*)&auxA0[rl];
        f32x4 a1v = *(const f32x4*)&auxA1[rl];
        int rbase = row0 + rl;
#pragma unroll
        for (int j = 0; j < 4; ++j) {
            int col = col0 + wn * 64 + j * 16 + (lane & 15);
#pragma unroll
            for (int r = 0; r < 4; ++r)
                att[((size_t)q * BATCH + rbase + r) * EDIM + col] =
                    f2b(a1v[r] * acc[i8][j][r] + a0v[r] * btAv[j] + a1v[r] * btBv[j]);
        }
    }
}

// ============ kernel 5: out = LN(xb + att) ============
__global__ __launch_bounds__(192) void k_fuse_ln(const unsigned short* __restrict__ xb,
                                                 const unsigned short* __restrict__ att,
                                                 const float* __restrict__ gamma,
                                                 const float* __restrict__ beta,
                                                 float* __restrict__ out) {
    __shared__ float red[2][3];
    int b = blockIdx.x, t = threadIdx.x, m = t >> 6, lane = t & 63;
    int e0 = lane * 8;
    s16x8 xv = *(const s16x8*)(xb + ((size_t)m * BATCH + b) * EDIM + e0);
    s16x8 av = *(const s16x8*)(att + ((size_t)m * BATCH + b) * EDIM + e0);
    float v[8]; float s = 0.f, s2 = 0.f;
#pragma unroll
    for (int j = 0; j < 8; ++j) {
        float vv = b2f((unsigned short)xv[j]) + b2f((unsigned short)av[j]);
        v[j] = vv; s += vv; s2 += vv * vv;
    }
    for (int off = 32; off; off >>= 1) { s += __shfl_xor(s, off, 64); s2 += __shfl_xor(s2, off, 64); }
    if (lane == 0) { red[0][m] = s; red[1][m] = s2; }
    __syncthreads();
    float S = red[0][0] + red[0][1] + red[0][2];
    float S2 = red[1][0] + red[1][1] + red[1][2];
    float mu  = S * (1.f / 1536.f);
    float var = S2 * (1.f / 1536.f) - mu * mu;
    float rs  = rsqrtf(var + 1e-5f);
    int f0 = m * EDIM + e0;
    f32x4 g0 = *(const f32x4*)(gamma + f0), g1 = *(const f32x4*)(gamma + f0 + 4);
    f32x4 be0 = *(const f32x4*)(beta + f0), be1 = *(const f32x4*)(beta + f0 + 4);
    f32x4 o0, o1;
#pragma unroll
    for (int j = 0; j < 4; ++j) {
        o0[j] = (v[j]     - mu) * rs * g0[j] + be0[j];
        o1[j] = (v[j + 4] - mu) * rs * g1[j] + be1[j];
    }
    float* op = out + (size_t)b * FEAT + f0;
    *(f32x4*)op = o0; *(f32x4*)(op + 4) = o1;
}

// ============ launcher ============
extern "C" void kernel_launch(void* const* d_in, const int* in_sizes, int n_in,
                              void* d_out, int out_size, void* d_ws, size_t ws_size,
                              hipStream_t stream) {
    const float* x     = (const float*)d_in[0];
    const float* Wq    = (const float*)d_in[1];
    const float* bq    = (const float*)d_in[2];
    const float* Wk    = (const float*)d_in[3];
    const float* bk    = (const float*)d_in[4];
    const float* v     = (const float*)d_in[5];
    const float* Wt    = (const float*)d_in[6];
    const float* bt    = (const float*)d_in[7];
    const float* gamma = (const float*)d_in[8];
    const float* beta  = (const float*)d_in[9];
    float* out = (float*)d_out;

    char* ws = (char*)d_ws;
    // layout (bytes):
    //   [0,         1572864)  wqk   bf16 3*512*512
    //   [1572864,   4718592)  wtt3  bf16 3*1024*512
    //   [4718592,   6291456)  alpha f32  6*65536
    //   [6291456, 207618048)  xb    bf16 3*65536*512
    //   [207618048,408944640) att   bf16 3*65536*512  (proj aliases; consumed first)
    unsigned short* wqk   = (unsigned short*)(ws);
    unsigned short* wtt3  = (unsigned short*)(ws + 1572864);
    float*          alpha = (float*)        (ws + 4718592);
    unsigned short* xb    = (unsigned short*)(ws + 6291456);
    unsigned short* att   = (unsigned short*)(ws + 207618048);
    unsigned short* proj  = att;  // proj fully consumed by k_scores before k_gemm_att writes att

    k_convert_x<<<4096, 256, 0, stream>>>(x, xb, (MOD * BATCH * EDIM) / 4);
    k_prep_w   <<<2048, 256, 0, stream>>>(Wq, Wk, Wt, wqk, wtt3);
    k_gemm_proj<<<1536, 512, 0, stream>>>(xb, wqk, bq, bk, proj);
    k_scores   <<<16384, 256, 0, stream>>>(proj, v, alpha);
    k_gemm_att <<<1536, 512, 0, stream>>>(xb, wtt3, alpha, bt, att);
    k_fuse_ln  <<<65536, 192, 0, stream>>>(xb, att, gamma, beta, out);
}